// Round 22
// baseline (39.520 us; speedup 1.0000x reference)
//
#include <hip/hip_runtime.h>

typedef float v2 __attribute__((ext_vector_type(2)));

#define W 512
#define H 512
#define OWID 506
#define OHT 506
#define BC 48              // 16 images * 3 channels
#define SEGOUT 26          // valid output cols per 16-lane segment (2/lane, q<=12)
#define WAVEOUT 104        // 4 segments
#define NSTRIP 5           // 5*104 = 520 >= 506
#define CH 28              // output rows per chunk (4 groups of 7)
#define NCG 5              // chunk-groups of 4 chunks; chunks 0..19 (19 is dead)
#define NWG (BC*NSTRIP*NCG)        // 1200 blocks
#define NWAVE (NWG*4)              // 4800 waves
#define NPIX 12289728.0f           // 16*3*506*506

__device__ __forceinline__ v2 clip2(v2 v) {
    const v2 z = {0.f, 0.f}, o = {1.f, 1.f};
    return __builtin_elementwise_min(__builtin_elementwise_max(v, z), o);
}

// DPP row_shl:N — lane p receives lane p+N within its 16-lane row; 0 if OOB.
template <int N>
__device__ __forceinline__ float dpp_shl(float v) {
    int r = __builtin_amdgcn_update_dpp(0, __float_as_int(v),
                                        0x100 + N, 0xF, 0xF, true);
    return __int_as_float(r);
}

// V = (even-col sum, odd-col sum). Returns (h for col 2q, h for col 2q+1).
__device__ __forceinline__ v2 hpair(v2 V) {
    float P  = V.x + V.y;
    float S2 = P + dpp_shl<1>(P);
    float S4 = S2 + dpp_shl<2>(S2);
    v2 h;
    h.x = S4 - dpp_shl<3>(V.y);
    h.y = S4 - V.x;
    return h;
}

// sum-domain SSIM (scaled by 49^4), packed over (even,odd) columns
__device__ __forceinline__ v2 ssim2(v2 a0, v2 a1, v2 az, v2 a4) {
    const v2 c1p  = {0.2401f, 0.2401f};          // C1 * 49^2
    const v2 c2p  = {2.1609f, 2.1609f};          // C2 * 49^2
    const v2 cvn  = {49.f/48.f, 49.f/48.f};
    const v2 cvn2 = {49.f/24.f, 49.f/24.f};
    const v2 k49  = {49.f, 49.f};
    const v2 k2   = {2.f, 2.f};
    v2 t01  = a0 * a1;
    v2 qs   = __builtin_elementwise_fma(a0, a0, a1 * a1);
    v2 w4   = __builtin_elementwise_fma(k49, a4, -t01);
    v2 num1 = __builtin_elementwise_fma(k2, t01, c1p);
    v2 num2 = __builtin_elementwise_fma(cvn2, w4, c2p);
    v2 w23  = __builtin_elementwise_fma(k49, az, -qs);
    v2 den1 = qs + c1p;
    v2 den2 = __builtin_elementwise_fma(cvn, w23, c2p);
    v2 num = num1 * num2;
    v2 den = den1 * den2;
    v2 r;
    r.x = __builtin_amdgcn_rcpf(den.x);
    r.y = __builtin_amdgcn_rcpf(den.y);
    return num * r;
}

__global__ __launch_bounds__(256)
void ssim_stream(const float* __restrict__ pred, const float* __restrict__ targ,
                 float* __restrict__ partial, float* __restrict__ out_atomic)
{
    // halo[w][j][lane]: wave w's init rows j=0..5 (clipped x0,x1,y0,y1)
    __shared__ float4 halo[4][6][64];

    // ---- bijective XCD swizzle (m204); NWG=1200 -> rr=0, wg = xcd*150 + idx ----
    const int orig = blockIdx.x;
    const int xcd  = orig & 7, idx = orig >> 3;
    const int qq = NWG >> 3, rr = NWG & 7;     // 150, 0
    const int wg = (xcd < rr ? xcd * (qq + 1) : rr * (qq + 1) + (xcd - rr) * qq) + idx;

    const int w    = __builtin_amdgcn_readfirstlane(threadIdx.x >> 6);  // wave 0..3
    const int lane = threadIdx.x & 63;
    const int seg  = lane >> 4;
    const int q    = lane & 15;

    // block -> (bc, cg, strip), strip-fastest for contiguous device-wide rows
    const int bs    = wg / NSTRIP;
    const int strip = wg - bs * NSTRIP;
    const int bc    = bs / NCG;
    const int cg    = bs - bc * NCG;
    const int chunk = 4 * cg + w;                // 0..19 (19 dead)

    const int ce = strip * WAVEOUT + seg * SEGOUT + 2 * q;  // even col this lane owns
    const int co = min(ce, W - 2);                          // clamped v2 col
    const bool oke = (q <= 12) && (ce     < OWID);
    const bool oko = (q <= 12) && (ce + 1 < OWID);

    const int oy0 = chunk * CH;                  // logical (may be 532)
    const int oyp = min(oy0, H - 8);             // physical load base (<= 504)
    const size_t base = (size_t)bc * (H * W) + (size_t)oyp * W;
    const float* __restrict__ px = pred + base;  // scalar base, row oyp
    const float* __restrict__ py = targ + base;

    // ---- init: ring rows 0..6, nx/ny = row 7 (rows oyp..oyp+7 <= 511) ----
    v2 ringx[7], ringy[7];
    v2 Vx = {0,0}, Vy = {0,0}, Vz = {0,0}, Vxy = {0,0};

    v2 nx = *(const v2*)(px + co);
    v2 ny = *(const v2*)(py + co);
    #pragma unroll
    for (int i = 0; i < 7; ++i) {
        v2 xr = nx, yr = ny;
        nx = *(const v2*)(px + (i + 1) * W + co);
        ny = *(const v2*)(py + (i + 1) * W + co);
        v2 x = clip2(xr), y = clip2(yr);
        ringx[i] = x; ringy[i] = y;
        Vx += x;
        Vy += y;
        Vz  += __builtin_elementwise_fma(x, x, y * y);
        Vxy += x * y;
    }

    // ---- publish this wave's first 6 rows for the previous chunk's wave ----
    if (w) {
        #pragma unroll
        for (int j = 0; j < 6; ++j)
            halo[w][j][lane] = make_float4(ringx[j].x, ringx[j].y,
                                           ringy[j].x, ringy[j].y);
    }
    __syncthreads();     // all waves reach this (no early exit above)

    // scalar prefetch pointers for row 8+, clamped
    const int r8 = min(oyp + 8, H - 1) - oyp;
    const float* fx = px + r8 * W;
    const float* fy = py + r8 * W;
    int rabs = oyp + 8;

    float acc = 0.f;

    #pragma unroll 1
    for (int g = 0; g < 4; ++g) {
        if (oy0 + 7 * g >= OHT) break;     // scalar early-exit (after barrier)
        #pragma unroll
        for (int i = 0; i < 7; ++i) {      // t = 7g+i; i compile-time
            const int t = g * 7 + i;
            // ---- emit output row oy0+t ----
            {
                v2 hx = hpair(Vx);
                v2 hy = hpair(Vy);
                v2 hz = hpair(Vz);
                v2 hw = hpair(Vxy);
                v2 v = ssim2(hx, hy, hz, hw);
                bool rok = (oy0 + t) < OHT;          // scalar
                acc += (oke && rok) ? v.x : 0.f;
                acc += (oko && rok) ? v.y : 0.f;
            }
            // ---- advance: consume row oy0+t+7, maybe prefetch row oy0+t+8 ----
            if (!(g == 3 && i == 6)) {               // t==27: nothing to advance
                v2 xo = ringx[i], yo = ringy[i];
                v2 xn, yn;
                // rows 28..33 (t=21..26, i.e. g==3, i<=5): w<3 takes them from
                // the next chunk's published init rows instead of global.
                if ((g == 3) && (i <= 5) && (w < 3)) {
                    float4 hh = halo[w + 1][i][lane];
                    xn.x = hh.x; xn.y = hh.y;
                    yn.x = hh.z; yn.y = hh.w;
                } else {
                    xn = clip2(nx); yn = clip2(ny);
                }
                // prefetch only while another nx-consume remains:
                // w<3: last nx consume at t=20 -> prefetch t<=19
                // w=3: last nx consume at t=26 -> prefetch t<=25
                const bool pre = (w == 3) ? (t <= 25) : (t <= 19);
                if (pre) {
                    nx = *(const v2*)(fx + co);
                    ny = *(const v2*)(fy + co);
                    if (rabs < H - 1) { fx += W; fy += W; }  // scalar guard
                    ++rabs;
                }
                Vx += xn - xo;
                Vy += yn - yo;
                v2 zn = __builtin_elementwise_fma(xn, xn, yn * yn);
                v2 zo = __builtin_elementwise_fma(xo, xo, yo * yo);
                Vz += zn - zo;
                Vxy += __builtin_elementwise_fma(xn, yn, -(xo * yo));
                ringx[i] = xn; ringy[i] = yn;
            }
        }
    }

    // ---- wave reduction, one partial per wave ----
    #pragma unroll
    for (int off = 32; off >= 1; off >>= 1)
        acc += __shfl_down(acc, off, 64);
    if (lane == 0) {
        const int wid = wg * 4 + w;
        if (partial) partial[wid] = acc;
        else atomicAdd(out_atomic, acc);
    }
}

__global__ __launch_bounds__(256)
void ssim_finish(const float* __restrict__ partial, float* __restrict__ out)
{
    __shared__ float red[4];
    float s = 0.f;
    for (int i = threadIdx.x; i < NWAVE; i += 256) s += partial[i];
    #pragma unroll
    for (int off = 32; off >= 1; off >>= 1)
        s += __shfl_down(s, off, 64);
    if ((threadIdx.x & 63) == 0) red[threadIdx.x >> 6] = s;
    __syncthreads();
    if (threadIdx.x == 0) {
        float t = red[0] + red[1] + red[2] + red[3];
        out[0] = 1.0f - t / NPIX;
    }
}

__global__ void ssim_zero(float* out) { out[0] = 0.0f; }
__global__ void ssim_finish_atomic(float* out) { out[0] = 1.0f - out[0] / NPIX; }

extern "C" void kernel_launch(void* const* d_in, const int* in_sizes, int n_in,
                              void* d_out, int out_size, void* d_ws, size_t ws_size,
                              hipStream_t stream) {
    const float* pred = (const float*)d_in[0];
    const float* targ = (const float*)d_in[1];
    float* out = (float*)d_out;

    dim3 block(256);
    dim3 grid(NWG);   // 1200 blocks, 4 waves each

    if (ws_size >= (size_t)NWAVE * sizeof(float)) {
        float* part = (float*)d_ws;
        ssim_stream<<<grid, block, 0, stream>>>(pred, targ, part, nullptr);
        ssim_finish<<<1, 256, 0, stream>>>(part, out);
    } else {
        ssim_zero<<<1, 1, 0, stream>>>(out);
        ssim_stream<<<grid, block, 0, stream>>>(pred, targ, nullptr, out);
        ssim_finish_atomic<<<1, 1, 0, stream>>>(out);
    }
}

// Round 23
// 39.126 us; speedup vs baseline: 1.0101x; 1.0101x over previous
//
#include <hip/hip_runtime.h>

typedef float v2 __attribute__((ext_vector_type(2)));

#define W 512
#define H 512
#define OWID 506
#define OHT 506
#define BC 48              // 16 images * 3 channels
#define SEGOUT 26          // valid output cols per 16-lane segment (2/lane, q<=12)
#define WAVEOUT 104        // 4 segments
#define NSTRIP 5           // 5*104 = 520 >= 506
#define CH 28              // output rows per chunk (4 groups of 7)
#define NCHUNK 19          // 19*28 = 532 >= 506
#define NWAVE (BC*NSTRIP*NCHUNK)   // 4560, divisible by 4
#define NWG   (NWAVE/4)            // 1140 blocks
#define NPIX 12289728.0f           // 16*3*506*506

__device__ __forceinline__ v2 clip2(v2 v) {
    const v2 z = {0.f, 0.f}, o = {1.f, 1.f};
    return __builtin_elementwise_min(__builtin_elementwise_max(v, z), o);
}

// DPP row_shl:N — lane p receives lane p+N within its 16-lane row; 0 if OOB.
template <int N>
__device__ __forceinline__ float dpp_shl(float v) {
    int r = __builtin_amdgcn_update_dpp(0, __float_as_int(v),
                                        0x100 + N, 0xF, 0xF, true);
    return __int_as_float(r);
}

// V = (even-col sum, odd-col sum). Returns (h for col 2q, h for col 2q+1).
__device__ __forceinline__ v2 hpair(v2 V) {
    float P  = V.x + V.y;
    float S2 = P + dpp_shl<1>(P);
    float S4 = S2 + dpp_shl<2>(S2);
    v2 h;
    h.x = S4 - dpp_shl<3>(V.y);
    h.y = S4 - V.x;
    return h;
}

// sum-domain SSIM (scaled by 49^4), packed over (even,odd) columns
__device__ __forceinline__ v2 ssim2(v2 a0, v2 a1, v2 az, v2 a4) {
    const v2 c1p  = {0.2401f, 0.2401f};          // C1 * 49^2
    const v2 c2p  = {2.1609f, 2.1609f};          // C2 * 49^2
    const v2 cvn  = {49.f/48.f, 49.f/48.f};
    const v2 cvn2 = {49.f/24.f, 49.f/24.f};
    const v2 k49  = {49.f, 49.f};
    const v2 k2   = {2.f, 2.f};
    v2 t01  = a0 * a1;
    v2 qs   = __builtin_elementwise_fma(a0, a0, a1 * a1);
    v2 w4   = __builtin_elementwise_fma(k49, a4, -t01);
    v2 num1 = __builtin_elementwise_fma(k2, t01, c1p);
    v2 num2 = __builtin_elementwise_fma(cvn2, w4, c2p);
    v2 w23  = __builtin_elementwise_fma(k49, az, -qs);
    v2 den1 = qs + c1p;
    v2 den2 = __builtin_elementwise_fma(cvn, w23, c2p);
    v2 num = num1 * num2;
    v2 den = den1 * den2;
    v2 r;
    r.x = __builtin_amdgcn_rcpf(den.x);
    r.y = __builtin_amdgcn_rcpf(den.y);
    return num * r;
}

__global__ __launch_bounds__(256)
void ssim_stream(const float* __restrict__ pred, const float* __restrict__ targ,
                 float* __restrict__ partial, float* __restrict__ out_atomic)
{
    // ---- bijective XCD swizzle (m204): contiguous wid span per XCD ----
    const int orig = blockIdx.x;
    const int xcd  = orig & 7, idx = orig >> 3;
    const int qq = NWG >> 3, rr = NWG & 7;     // 142, 4
    const int wg = (xcd < rr ? xcd * (qq + 1) : rr * (qq + 1) + (xcd - rr) * qq) + idx;

    const int wid  = __builtin_amdgcn_readfirstlane(wg * 4 + (threadIdx.x >> 6));
    const int lane = threadIdx.x & 63;
    const int seg  = lane >> 4;
    const int q    = lane & 15;

    // STRIP-FASTEST decomposition (R16): co-dispatched waves = 5 strips of the
    // same (image, row-chunk) -> contiguous 2KB device-wide row reads.
    const int bc    = wid / (NSTRIP * NCHUNK);
    const int rem   = wid - bc * (NSTRIP * NCHUNK);
    const int chunk = rem / NSTRIP;
    const int strip = rem - chunk * NSTRIP;

    const int ce = strip * WAVEOUT + seg * SEGOUT + 2 * q;  // even col this lane owns
    const int co = min(ce, W - 2);                          // clamped v2 col
    const bool oke = (q <= 12) && (ce     < OWID);
    const bool oko = (q <= 12) && (ce + 1 < OWID);

    const int oy0 = chunk * CH;                  // <= 504
    const size_t base = (size_t)bc * (H * W) + (size_t)oy0 * W;
    const float* __restrict__ px = pred + base;  // scalar base, row oy0
    const float* __restrict__ py = targ + base;

    // ---- vertical-first state: ring of clipped pairs, running pair sums ----
    v2 ringx[7], ringy[7];
    v2 Vx = {0,0}, Vy = {0,0}, Vz = {0,0}, Vxy = {0,0};

    v2 nx = *(const v2*)(px + co);
    v2 ny = *(const v2*)(py + co);
    #pragma unroll
    for (int i = 0; i < 7; ++i) {
        v2 xr = nx, yr = ny;
        nx = *(const v2*)(px + (i + 1) * W + co);   // rows 1..7 (<=511)
        ny = *(const v2*)(py + (i + 1) * W + co);
        v2 x = clip2(xr), y = clip2(yr);
        ringx[i] = x; ringy[i] = y;
        Vx += x;
        Vy += y;
        Vz  += __builtin_elementwise_fma(x, x, y * y);
        Vxy += x * y;
    }
    // nx/ny hold row 7. Scalar prefetch pointers for row 8+, clamped.
    const int r8 = min(oy0 + 8, H - 1) - oy0;
    const float* fx = px + r8 * W;
    const float* fy = py + r8 * W;
    int rabs = oy0 + 8;

    float acc = 0.f;

    #pragma unroll 1
    for (int g = 0; g < 4; ++g) {
        if (oy0 + 7 * g >= OHT) break;     // scalar early-exit (last chunk)
        #pragma unroll
        for (int i = 0; i < 7; ++i) {      // t = 7g+i, ring slot i (static)
            const int t = g * 7 + i;
            // ---- emit output row oy0+t: shared-ladder h-pairs, packed SSIM ----
            {
                v2 hx = hpair(Vx);
                v2 hy = hpair(Vy);
                v2 hz = hpair(Vz);
                v2 hw = hpair(Vxy);
                v2 v = ssim2(hx, hy, hz, hw);
                bool rok = (oy0 + t) < OHT;          // scalar
                acc += (oke && rok) ? v.x : 0.f;
                acc += (oko && rok) ? v.y : 0.f;
            }
            // ---- advance: consume prefetched row t+7, prefetch row t+8 ----
            // Trim (R23): advance at t==27 feeds no emit -> skip entirely.
            // Both conditions are scalar (g runtime-scalar, i unrolled const).
            if (!(g == 3 && i == 6)) {
                v2 xo = ringx[i], yo = ringy[i];
                v2 xn = clip2(nx), yn = clip2(ny);
                // Prefetch only while a future consume exists: last consume is
                // at t==26 (row 33), which was prefetched at t==25.
                if (t <= 25) {
                    nx = *(const v2*)(fx + co);
                    ny = *(const v2*)(fy + co);
                    if (rabs < H - 1) { fx += W; fy += W; }  // scalar guard
                    ++rabs;
                }
                Vx += xn - xo;
                Vy += yn - yo;
                v2 zn = __builtin_elementwise_fma(xn, xn, yn * yn);
                v2 zo = __builtin_elementwise_fma(xo, xo, yo * yo);
                Vz += zn - zo;
                Vxy += __builtin_elementwise_fma(xn, yn, -(xo * yo));
                ringx[i] = xn; ringy[i] = yn;
            }
        }
    }

    // ---- wave reduction, one partial per wave ----
    #pragma unroll
    for (int off = 32; off >= 1; off >>= 1)
        acc += __shfl_down(acc, off, 64);
    if (lane == 0) {
        if (partial) partial[wid] = acc;
        else atomicAdd(out_atomic, acc);
    }
}

__global__ __launch_bounds__(256)
void ssim_finish(const float* __restrict__ partial, float* __restrict__ out)
{
    __shared__ float red[4];
    float s = 0.f;
    for (int i = threadIdx.x; i < NWAVE; i += 256) s += partial[i];
    #pragma unroll
    for (int off = 32; off >= 1; off >>= 1)
        s += __shfl_down(s, off, 64);
    if ((threadIdx.x & 63) == 0) red[threadIdx.x >> 6] = s;
    __syncthreads();
    if (threadIdx.x == 0) {
        float t = red[0] + red[1] + red[2] + red[3];
        out[0] = 1.0f - t / NPIX;
    }
}

__global__ void ssim_zero(float* out) { out[0] = 0.0f; }
__global__ void ssim_finish_atomic(float* out) { out[0] = 1.0f - out[0] / NPIX; }

extern "C" void kernel_launch(void* const* d_in, const int* in_sizes, int n_in,
                              void* d_out, int out_size, void* d_ws, size_t ws_size,
                              hipStream_t stream) {
    const float* pred = (const float*)d_in[0];
    const float* targ = (const float*)d_in[1];
    float* out = (float*)d_out;

    dim3 block(256);
    dim3 grid(NWG);   // 1140 blocks, 4 waves each

    if (ws_size >= (size_t)NWAVE * sizeof(float)) {
        float* part = (float*)d_ws;
        ssim_stream<<<grid, block, 0, stream>>>(pred, targ, part, nullptr);
        ssim_finish<<<1, 256, 0, stream>>>(part, out);
    } else {
        ssim_zero<<<1, 1, 0, stream>>>(out);
        ssim_stream<<<grid, block, 0, stream>>>(pred, targ, nullptr, out);
        ssim_finish_atomic<<<1, 1, 0, stream>>>(out);
    }
}

// Round 24
// 33.027 us; speedup vs baseline: 1.1966x; 1.1847x over previous
//
#include <hip/hip_runtime.h>

typedef float v2 __attribute__((ext_vector_type(2)));

#define W 512
#define H 512
#define OWID 506
#define OHT 506
#define BC 48              // 16 images * 3 channels
#define SEGOUT 26          // valid output cols per 16-lane segment (2/lane, q<=12)
#define WAVEOUT 104        // 4 segments
#define NSTRIP 5           // 5*104 = 520 >= 506
#define CH 28              // output rows per chunk (4 groups of 7)
#define NCHUNK 19          // 19*28 = 532 >= 506
#define NWAVE (BC*NSTRIP*NCHUNK)   // 4560, divisible by 4
#define NWG   (NWAVE/4)            // 1140 blocks
#define NPIX 12289728.0f           // 16*3*506*506

__device__ __forceinline__ v2 clip2(v2 v) {
    const v2 z = {0.f, 0.f}, o = {1.f, 1.f};
    return __builtin_elementwise_min(__builtin_elementwise_max(v, z), o);
}

// DPP row_shl:N — lane p receives lane p+N within its 16-lane row; 0 if OOB.
template <int N>
__device__ __forceinline__ float dpp_shl(float v) {
    int r = __builtin_amdgcn_update_dpp(0, __float_as_int(v),
                                        0x100 + N, 0xF, 0xF, true);
    return __int_as_float(r);
}

// V = (even-col sum, odd-col sum). Returns (h for col 2q, h for col 2q+1).
__device__ __forceinline__ v2 hpair(v2 V) {
    float P  = V.x + V.y;
    float S2 = P + dpp_shl<1>(P);
    float S4 = S2 + dpp_shl<2>(S2);
    v2 h;
    h.x = S4 - dpp_shl<3>(V.y);
    h.y = S4 - V.x;
    return h;
}

// sum-domain SSIM (scaled by 49^4), packed over (even,odd) columns
__device__ __forceinline__ v2 ssim2(v2 a0, v2 a1, v2 az, v2 a4) {
    const v2 c1p  = {0.2401f, 0.2401f};          // C1 * 49^2
    const v2 c2p  = {2.1609f, 2.1609f};          // C2 * 49^2
    const v2 cvn  = {49.f/48.f, 49.f/48.f};
    const v2 cvn2 = {49.f/24.f, 49.f/24.f};
    const v2 k49  = {49.f, 49.f};
    const v2 k2   = {2.f, 2.f};
    v2 t01  = a0 * a1;
    v2 qs   = __builtin_elementwise_fma(a0, a0, a1 * a1);
    v2 w4   = __builtin_elementwise_fma(k49, a4, -t01);
    v2 num1 = __builtin_elementwise_fma(k2, t01, c1p);
    v2 num2 = __builtin_elementwise_fma(cvn2, w4, c2p);
    v2 w23  = __builtin_elementwise_fma(k49, az, -qs);
    v2 den1 = qs + c1p;
    v2 den2 = __builtin_elementwise_fma(cvn, w23, c2p);
    v2 num = num1 * num2;
    v2 den = den1 * den2;
    v2 r;
    r.x = __builtin_amdgcn_rcpf(den.x);
    r.y = __builtin_amdgcn_rcpf(den.y);
    return num * r;
}

__global__ __launch_bounds__(256)
void ssim_stream(const float* __restrict__ pred, const float* __restrict__ targ,
                 float* __restrict__ partial, float* __restrict__ out_atomic)
{
    // ---- bijective XCD swizzle (m204): contiguous wid span per XCD ----
    const int orig = blockIdx.x;
    const int xcd  = orig & 7, idx = orig >> 3;
    const int qq = NWG >> 3, rr = NWG & 7;     // 142, 4
    const int wg = (xcd < rr ? xcd * (qq + 1) : rr * (qq + 1) + (xcd - rr) * qq) + idx;

    const int wid  = __builtin_amdgcn_readfirstlane(wg * 4 + (threadIdx.x >> 6));
    const int lane = threadIdx.x & 63;
    const int seg  = lane >> 4;
    const int q    = lane & 15;

    // STRIP-FASTEST decomposition (R16): co-dispatched waves = 5 strips of the
    // same (image, row-chunk) -> contiguous 2KB device-wide row reads.
    const int bc    = wid / (NSTRIP * NCHUNK);
    const int rem   = wid - bc * (NSTRIP * NCHUNK);
    const int chunk = rem / NSTRIP;
    const int strip = rem - chunk * NSTRIP;

    const int ce = strip * WAVEOUT + seg * SEGOUT + 2 * q;  // even col this lane owns
    const int co = min(ce, W - 2);                          // clamped v2 col
    const bool oke = (q <= 12) && (ce     < OWID);
    const bool oko = (q <= 12) && (ce + 1 < OWID);

    const int oy0 = chunk * CH;                  // <= 504
    const size_t base = (size_t)bc * (H * W) + (size_t)oy0 * W;
    const float* __restrict__ px = pred + base;  // scalar base, row oy0
    const float* __restrict__ py = targ + base;

    // ---- vertical-first state: ring of clipped pairs, running pair sums ----
    v2 ringx[7], ringy[7];
    v2 Vx = {0,0}, Vy = {0,0}, Vz = {0,0}, Vxy = {0,0};

    v2 nx = *(const v2*)(px + co);
    v2 ny = *(const v2*)(py + co);
    #pragma unroll
    for (int i = 0; i < 7; ++i) {
        v2 xr = nx, yr = ny;
        nx = *(const v2*)(px + (i + 1) * W + co);   // rows 1..7 (<=511)
        ny = *(const v2*)(py + (i + 1) * W + co);
        v2 x = clip2(xr), y = clip2(yr);
        ringx[i] = x; ringy[i] = y;
        Vx += x;
        Vy += y;
        Vz  += __builtin_elementwise_fma(x, x, y * y);
        Vxy += x * y;
    }
    // nx/ny hold row 7. Scalar prefetch pointers for row 8+, clamped.
    const int r8 = min(oy0 + 8, H - 1) - oy0;
    const float* fx = px + r8 * W;
    const float* fy = py + r8 * W;
    int rabs = oy0 + 8;

    float acc = 0.f;

    #pragma unroll 1
    for (int g = 0; g < 4; ++g) {
        if (oy0 + 7 * g >= OHT) break;     // scalar early-exit (last chunk)
        #pragma unroll
        for (int i = 0; i < 7; ++i) {      // t = 7g+i, ring slot i (static)
            const int t = g * 7 + i;
            // ---- emit output row oy0+t: shared-ladder h-pairs, packed SSIM ----
            {
                v2 hx = hpair(Vx);
                v2 hy = hpair(Vy);
                v2 hz = hpair(Vz);
                v2 hw = hpair(Vxy);
                v2 v = ssim2(hx, hy, hz, hw);
                bool rok = (oy0 + t) < OHT;          // scalar
                acc += (oke && rok) ? v.x : 0.f;
                acc += (oko && rok) ? v.y : 0.f;
            }
            // ---- advance: consume prefetched row t+7, prefetch row t+8 ----
            {
                v2 xo = ringx[i], yo = ringy[i];
                v2 xn = clip2(nx), yn = clip2(ny);
                nx = *(const v2*)(fx + co);
                ny = *(const v2*)(fy + co);
                if (rabs < H - 1) { fx += W; fy += W; }  // scalar guard
                ++rabs;
                Vx += xn - xo;
                Vy += yn - yo;
                v2 zn = __builtin_elementwise_fma(xn, xn, yn * yn);
                v2 zo = __builtin_elementwise_fma(xo, xo, yo * yo);
                Vz += zn - zo;
                Vxy += __builtin_elementwise_fma(xn, yn, -(xo * yo));
                ringx[i] = xn; ringy[i] = yn;
            }
        }
    }

    // ---- wave reduction, one partial per wave ----
    #pragma unroll
    for (int off = 32; off >= 1; off >>= 1)
        acc += __shfl_down(acc, off, 64);
    if (lane == 0) {
        if (partial) partial[wid] = acc;
        else atomicAdd(out_atomic, acc);
    }
}

__global__ __launch_bounds__(256)
void ssim_finish(const float* __restrict__ partial, float* __restrict__ out)
{
    __shared__ float red[4];
    float s = 0.f;
    for (int i = threadIdx.x; i < NWAVE; i += 256) s += partial[i];
    #pragma unroll
    for (int off = 32; off >= 1; off >>= 1)
        s += __shfl_down(s, off, 64);
    if ((threadIdx.x & 63) == 0) red[threadIdx.x >> 6] = s;
    __syncthreads();
    if (threadIdx.x == 0) {
        float t = red[0] + red[1] + red[2] + red[3];
        out[0] = 1.0f - t / NPIX;
    }
}

__global__ void ssim_zero(float* out) { out[0] = 0.0f; }
__global__ void ssim_finish_atomic(float* out) { out[0] = 1.0f - out[0] / NPIX; }

extern "C" void kernel_launch(void* const* d_in, const int* in_sizes, int n_in,
                              void* d_out, int out_size, void* d_ws, size_t ws_size,
                              hipStream_t stream) {
    const float* pred = (const float*)d_in[0];
    const float* targ = (const float*)d_in[1];
    float* out = (float*)d_out;

    dim3 block(256);
    dim3 grid(NWG);   // 1140 blocks, 4 waves each

    if (ws_size >= (size_t)NWAVE * sizeof(float)) {
        float* part = (float*)d_ws;
        ssim_stream<<<grid, block, 0, stream>>>(pred, targ, part, nullptr);
        ssim_finish<<<1, 256, 0, stream>>>(part, out);
    } else {
        ssim_zero<<<1, 1, 0, stream>>>(out);
        ssim_stream<<<grid, block, 0, stream>>>(pred, targ, nullptr, out);
        ssim_finish_atomic<<<1, 1, 0, stream>>>(out);
    }
}